// Round 1
// baseline (555.629 us; speedup 1.0000x reference)
//
#include <hip/hip_runtime.h>

using bf16x8 = __attribute__((ext_vector_type(8))) __bf16;
using f32x4  = __attribute__((ext_vector_type(4))) float;
using u16x8  = __attribute__((ext_vector_type(8))) unsigned short;

__device__ __forceinline__ unsigned short f2bf(float x) {
  unsigned int u = __float_as_uint(x);
  u += 0x7fffu + ((u >> 16) & 1u);   // RNE
  return (unsigned short)(u >> 16);
}

__device__ __forceinline__ void gload16(const unsigned short* g, unsigned short* l) {
  __builtin_amdgcn_global_load_lds(
      (__attribute__((address_space(1))) void*)const_cast<unsigned short*>(g),
      (__attribute__((address_space(3))) void*)l, 16, 0, 0);
}

// ---------------- fp32 -> bf16 convert (float4 / ushort4 vectorized) ----------------
__global__ __launch_bounds__(256) void cvt_kernel(const float* __restrict__ in,
                                                  unsigned short* __restrict__ out) {
  const int i = blockIdx.x * 256 + threadIdx.x;
  const float4 v = ((const float4*)in)[i];
  ushort4 o;
  o.x = f2bf(v.x); o.y = f2bf(v.y); o.z = f2bf(v.z); o.w = f2bf(v.w);
  ((ushort4*)out)[i] = o;
}

// ---------------- NT GEMM: C[M,N] = A[M,K] * B[N,K]^T, bf16 in, fp32 acc ----------------
// 128x128 tile, BK=32, 256 threads = 4 waves (2x2), each wave 64x64 = 4x4 frags of 16x16x32.
// MODE 0: write bf16 to QKV buffer laid out [which][b][h][s][d] (fused reshape/transpose)
// MODE 1: write fp32 row-major to Cf
template<int MODE>
__global__ __launch_bounds__(256)
void gemm_nt(const unsigned short* __restrict__ A,
             const unsigned short* __restrict__ Bw,
             float* __restrict__ Cf,
             unsigned short* __restrict__ Cq,
             int M, int N, int K)
{
  __shared__ unsigned short As[128 * 32];
  __shared__ unsigned short Bs[128 * 32];
  const int tid  = threadIdx.x;
  const int lane = tid & 63;
  const int wid  = tid >> 6;
  const int wr = wid >> 1, wc = wid & 1;
  const int lrow = lane & 15, lhi = lane >> 4;
  const int bn = blockIdx.x * 128;
  const int bm = blockIdx.y * 128;

  f32x4 acc[4][4] = {};

  // staging: idx = issue*256 + tid covers 16B; row = idx>>2, col8 = (idx&3)*8 -> lds off idx*8
  const int srow = tid >> 2;
  const int scol = (tid & 3) * 8;
  const unsigned short* Ag0 = A  + (size_t)(bm + srow) * K + scol;
  const unsigned short* Ag1 = Ag0 + (size_t)64 * K;
  const unsigned short* Bg0 = Bw + (size_t)(bn + srow) * K + scol;
  const unsigned short* Bg1 = Bg0 + (size_t)64 * K;
  unsigned short* Ad0 = As + tid * 8;
  unsigned short* Ad1 = As + (256 + tid) * 8;
  unsigned short* Bd0 = Bs + tid * 8;
  unsigned short* Bd1 = Bs + (256 + tid) * 8;

  for (int k0 = 0; k0 < K; k0 += 32) {
    gload16(Ag0 + k0, Ad0);
    gload16(Ag1 + k0, Ad1);
    gload16(Bg0 + k0, Bd0);
    gload16(Bg1 + k0, Bd1);
    __syncthreads();   // implicit vmcnt(0) drains global_load_lds
    bf16x8 af[4], bfr[4];
#pragma unroll
    for (int m = 0; m < 4; ++m)
      af[m] = *(const bf16x8*)(As + (wr * 64 + m * 16 + lrow) * 32 + lhi * 8);
#pragma unroll
    for (int n = 0; n < 4; ++n)
      bfr[n] = *(const bf16x8*)(Bs + (wc * 64 + n * 16 + lrow) * 32 + lhi * 8);
#pragma unroll
    for (int m = 0; m < 4; ++m)
#pragma unroll
      for (int n = 0; n < 4; ++n)
        acc[m][n] = __builtin_amdgcn_mfma_f32_16x16x32_bf16(af[m], bfr[n], acc[m][n], 0, 0, 0);
    __syncthreads();
  }

  // C/D layout: col = lane&15, row = (lane>>4)*4 + r   [m89-verified]
#pragma unroll
  for (int m = 0; m < 4; ++m) {
    const int row0 = bm + wr * 64 + m * 16 + lhi * 4;
#pragma unroll
    for (int n = 0; n < 4; ++n) {
      const int col = bn + wc * 64 + n * 16 + lrow;
#pragma unroll
      for (int r = 0; r < 4; ++r) {
        const int row = row0 + r;
        const float v = acc[m][n][r];
        if (MODE == 0) {
          // col in [0,6144): which = Q/K/V; row in [0,4096): b,s
          const int which = col >> 11;
          const int h = (col >> 6) & 31;
          const int d = col & 63;
          const int b = row >> 11;
          const int s = row & 2047;
          Cq[(((size_t)which * 64 + b * 32 + h) * 2048 + s) * 64 + d] = f2bf(v);
        } else {
          Cf[(size_t)row * N + col] = v;
        }
      }
    }
  }
}

// ---------------- flash attention: 1 block = (bh, 64 q-rows), 4 waves x 16 rows ----------------
__global__ __launch_bounds__(256)
void attn_kernel(const unsigned short* __restrict__ QKV,
                 const float* __restrict__ mask,
                 unsigned short* __restrict__ Ctx)
{
  constexpr int S = 2048, D = 64, BH = 64;
  __shared__ unsigned short Klds[64 * 64];      // [key][d], K-chunk swizzled via global src
  __shared__ unsigned short VT[64 * 64];        // [d][key], swizzled
  __shared__ unsigned short Plds[4][16 * 64];   // per-wave P, swizzled
  __shared__ float mlds[64];

  const int tid  = threadIdx.x;
  const int lane = tid & 63;
  const int wid  = tid >> 6;
  const int lrow = lane & 15;
  const int lhi  = lane >> 4;
  const int bh = blockIdx.y;
  const int b  = bh >> 5;
  const int h  = bh & 31;
  const int qbase = blockIdx.x * 64;

  const size_t qoff = (size_t)bh * S * D;
  const size_t koff = qoff + (size_t)BH * S * D;
  const size_t voff = koff + (size_t)BH * S * D;

  // hoist Q fragments: A-frag lane l holds Q[row=l%16][k = 8*(l>>4)+j (+32*ks)]
  bf16x8 qa[2];
  {
    const unsigned short* Qp = QKV + qoff + (size_t)(qbase + wid * 16 + lrow) * D + lhi * 8;
    qa[0] = *(const bf16x8*)(Qp);
    qa[1] = *(const bf16x8*)(Qp + 32);
  }

  f32x4 oacc[4] = {};
  float mrow[4] = {-1e30f, -1e30f, -1e30f, -1e30f};
  float srow[4] = {0.f, 0.f, 0.f, 0.f};

  // K staging: idx*16B -> row=idx>>3, lds-chunk=idx&7; fetch global chunk (idx&7)^(row&7)
  const int krow = tid >> 3;
  const int kcol = (((tid & 7) ^ (krow & 7)) << 3);
  unsigned short* Kd0 = Klds + tid * 8;
  unsigned short* Kd1 = Klds + (256 + tid) * 8;

  const int vrow  = tid >> 2;          // V source row (key)
  const int vcol0 = (tid & 3) * 16;    // V source col (d)

  const float k1 = 0.125f * 1.44269504f;  // (1/sqrt(64)) * log2(e)

  for (int t = 0; t < S / 64; ++t) {
    const int kb = t * 64;
    gload16(QKV + koff + (size_t)(kb + krow) * D + kcol, Kd0);
    gload16(QKV + koff + (size_t)(kb + 32 + krow) * D + kcol, Kd1);
    {
      // V tile transposed into VT with chunk ^= (dc&7)^(dc>>4) swizzle
      const unsigned short* Vp = QKV + voff + (size_t)(kb + vrow) * D + vcol0;
      u16x8 v0 = *(const u16x8*)(Vp);
      u16x8 v1 = *(const u16x8*)(Vp + 8);
#pragma unroll
      for (int j = 0; j < 8; ++j) {
        const int dc = vcol0 + j;
        VT[dc * 64 + (((vrow >> 3) ^ (dc & 7) ^ (dc >> 4)) << 3) + (vrow & 7)] = v0[j];
      }
#pragma unroll
      for (int j = 0; j < 8; ++j) {
        const int dc = vcol0 + 8 + j;
        VT[dc * 64 + (((vrow >> 3) ^ (dc & 7) ^ (dc >> 4)) << 3) + (vrow & 7)] = v1[j];
      }
    }
    if (tid < 64) mlds[tid] = mask[(size_t)b * S + kb + tid] * 1.44269504f;
    __syncthreads();

    // ---- QK^T: scores strip [16 x 64] per wave ----
    f32x4 sacc[4] = {};
#pragma unroll
    for (int f = 0; f < 4; ++f) {
      const int krw = f * 16 + lrow;
      bf16x8 kf0 = *(const bf16x8*)(Klds + krw * 64 + ((lhi ^ (lrow & 7)) << 3));
      bf16x8 kf1 = *(const bf16x8*)(Klds + krw * 64 + (((lhi + 4) ^ (lrow & 7)) << 3));
      sacc[f] = __builtin_amdgcn_mfma_f32_16x16x32_bf16(qa[0], kf0, sacc[f], 0, 0, 0);
      sacc[f] = __builtin_amdgcn_mfma_f32_16x16x32_bf16(qa[1], kf1, sacc[f], 0, 0, 0);
    }

    // ---- online softmax (log2 domain); row stats across the 16-lane group ----
    float pm[4] = {-1e30f, -1e30f, -1e30f, -1e30f};
#pragma unroll
    for (int f = 0; f < 4; ++f) {
      const float mk = mlds[lrow + 16 * f];
#pragma unroll
      for (int r = 0; r < 4; ++r) {
        float v = sacc[f][r] * k1 + mk;
        sacc[f][r] = v;
        pm[r] = fmaxf(pm[r], v);
      }
    }
#pragma unroll
    for (int off = 1; off < 16; off <<= 1)
#pragma unroll
      for (int r = 0; r < 4; ++r)
        pm[r] = fmaxf(pm[r], __shfl_xor(pm[r], off, 64));
#pragma unroll
    for (int r = 0; r < 4; ++r) {
      const float mnew  = fmaxf(mrow[r], pm[r]);
      const float alpha = exp2f(mrow[r] - mnew);
      mrow[r] = mnew;
      srow[r] *= alpha;
#pragma unroll
      for (int f = 0; f < 4; ++f) oacc[f][r] *= alpha;
      float ps = 0.f;
#pragma unroll
      for (int f = 0; f < 4; ++f) {
        const float p = exp2f(sacc[f][r] - mnew);
        sacc[f][r] = p;
        ps += p;
      }
      srow[r] += ps;   // per-lane partial; reduced across group after the loop
    }

    // ---- P -> LDS (bf16, swizzled); acc layout: lane holds P[lhi*4+r][lrow+16f] ----
    unsigned short* Pw = &Plds[wid][0];
#pragma unroll
    for (int f = 0; f < 4; ++f) {
      const int key = lrow + 16 * f;
#pragma unroll
      for (int r = 0; r < 4; ++r) {
        const int rho = lhi * 4 + r;
        Pw[rho * 64 + ((((key >> 3) ^ (rho & 7))) << 3) + (key & 7)] = f2bf(sacc[f][r]);
      }
    }

    // ---- PV: O += P[16x64] * V[64x64] ----
#pragma unroll
    for (int ks = 0; ks < 2; ++ks) {
      bf16x8 pa = *(const bf16x8*)(Pw + lrow * 64 + (((lhi + 4 * ks) ^ (lrow & 7)) << 3));
#pragma unroll
      for (int f = 0; f < 4; ++f) {
        const int dc = lrow + 16 * f;
        bf16x8 vb = *(const bf16x8*)(VT + dc * 64 + (((lhi + 4 * ks) ^ (dc & 7) ^ (dc >> 4)) << 3));
        oacc[f] = __builtin_amdgcn_mfma_f32_16x16x32_bf16(pa, vb, oacc[f], 0, 0, 0);
      }
    }
    __syncthreads();
  }

  // final sum-reduce across the 16-lane group
#pragma unroll
  for (int off = 1; off < 16; off <<= 1)
#pragma unroll
    for (int r = 0; r < 4; ++r)
      srow[r] += __shfl_xor(srow[r], off, 64);

  // write ctx [B,S,HID] bf16, fusing the [B,H,S,D] -> [B,S,H*D] transpose
#pragma unroll
  for (int f = 0; f < 4; ++f) {
    const int d = lrow + 16 * f;
#pragma unroll
    for (int r = 0; r < 4; ++r) {
      const int q = qbase + wid * 16 + lhi * 4 + r;
      const float v = oacc[f][r] / srow[r];
      Ctx[((size_t)b * S + q) * 2048 + h * 64 + d] = f2bf(v);
    }
  }
}

// ---------------- launch ----------------
extern "C" void kernel_launch(void* const* d_in, const int* in_sizes, int n_in,
                              void* d_out, int out_size, void* d_ws, size_t ws_size,
                              hipStream_t stream) {
  const float* X    = (const float*)d_in[0];
  const float* mask = (const float*)d_in[1];
  const float* wq   = (const float*)d_in[2];
  const float* wk   = (const float*)d_in[3];
  const float* wv   = (const float*)d_in[4];
  const float* wo   = (const float*)d_in[5];

  // workspace layout (ushort elements): 112 MB total
  unsigned short* ws   = (unsigned short*)d_ws;
  unsigned short* Xb   = ws;                    //  8,388,608  X bf16 [4096][2048]
  unsigned short* Wcat = Xb + 8388608;          // 12,582,912  [Wq;Wk;Wv] bf16 [6144][2048]
  unsigned short* Wob  = Wcat + 12582912;       //  4,194,304  Wo bf16 [2048][2048]
  unsigned short* QKVb = Wob + 4194304;         // 25,165,824  [3][64][2048][64]
  unsigned short* Ctxb = QKVb + 25165824;       //  8,388,608  ctx bf16 [4096][2048]

  cvt_kernel<<<8192, 256, 0, stream>>>(X, Xb);
  cvt_kernel<<<4096, 256, 0, stream>>>(wq, Wcat);
  cvt_kernel<<<4096, 256, 0, stream>>>(wk, Wcat + 4194304);
  cvt_kernel<<<4096, 256, 0, stream>>>(wv, Wcat + 8388608);
  cvt_kernel<<<4096, 256, 0, stream>>>(wo, Wob);

  // QKV projection: [4096x2048] x [6144x2048]^T, epilogue scatters to [which][b][h][s][d]
  gemm_nt<0><<<dim3(48, 32), 256, 0, stream>>>(Xb, Wcat, nullptr, QKVb, 4096, 6144, 2048);

  // flash attention over 64 (b,h) pairs x 32 q-tiles
  attn_kernel<<<dim3(32, 64), 256, 0, stream>>>(QKVb, mask, Ctxb);

  // output projection: [4096x2048] x [2048x2048]^T -> fp32 d_out
  gemm_nt<1><<<dim3(16, 32), 256, 0, stream>>>(Ctxb, Wob, (float*)d_out, nullptr, 4096, 2048, 2048);
}